// Round 1
// baseline (279.579 us; speedup 1.0000x reference)
//
#include <hip/hip_runtime.h>

// PGNN: N=50000 nodes, K=32 anchors/edges per node, E=1.6M edges
// in:  feat[N,128], dists[N,32], src[E], dst[E], weights...
// out: normalize(out_position)[N,32] f32
constexpr int NN = 50000;
constexpr int KANCH = 32;

static __device__ __forceinline__ float bf2f(unsigned short u) {
    return __uint_as_float(((unsigned int)u) << 16);
}
static __device__ __forceinline__ unsigned short f2bf(float f) {
    unsigned int x = __float_as_uint(f);
    x += 0x7FFFu + ((x >> 16) & 1u);   // round-to-nearest-even
    return (unsigned short)(x >> 16);
}

// ---------------------------------------------------------------------------
// K0: compose layer-1 weights through the pre-linear.
// wu_eff = Wu1 @ w_pre  [64,128];  bu_eff = Wu1 @ b_pre + bu1  [64]
// ---------------------------------------------------------------------------
__global__ __launch_bounds__(256) void k_combine(
    const float* __restrict__ w_pre, const float* __restrict__ b_pre,
    const float* __restrict__ Wu1, const float* __restrict__ bu1,
    const float* __restrict__ Wv1, const float* __restrict__ bv1,
    float* __restrict__ wu_eff, float* __restrict__ wv_eff,
    float* __restrict__ bu_eff, float* __restrict__ bv_eff)
{
    int gid = blockIdx.x * 256 + threadIdx.x;
    if (gid < 8192) {
        int j = gid >> 7, i = gid & 127;
        float a = 0.f;
        for (int t = 0; t < 64; ++t) a += Wu1[j * 64 + t] * w_pre[t * 128 + i];
        wu_eff[gid] = a;
    } else if (gid < 16384) {
        int g = gid - 8192;
        int j = g >> 7, i = g & 127;
        float a = 0.f;
        for (int t = 0; t < 64; ++t) a += Wv1[j * 64 + t] * w_pre[t * 128 + i];
        wv_eff[g] = a;
    } else if (gid < 16448) {
        int j = gid - 16384;
        float a = bu1[j];
        for (int t = 0; t < 64; ++t) a += Wu1[j * 64 + t] * b_pre[t];
        bu_eff[j] = a;
    } else if (gid < 16512) {
        int j = gid - 16448;
        float a = bv1[j];
        for (int t = 0; t < 64; ++t) a += Wv1[j * 64 + t] * b_pre[t];
        bv_eff[j] = a;
    }
}

// ---------------------------------------------------------------------------
// K1: out[n][j] = bf16( B[j] + sum_i W[j][i] * feat[n][i] ),  in=128, out=64.
// Wave-task = 8 nodes; lane = output dim j. Weights from LDS (b128,
// linear-equivalent stride 33 float4). feat via wave-uniform loads
// (readfirstlane-pinned wave id -> scalar loads on the SGPR pipe).
// ---------------------------------------------------------------------------
__global__ __launch_bounds__(256) void k_lin128(
    const float4* __restrict__ featv4,          // [NN*32]
    const float* __restrict__ W,                // [64][128]
    const float* __restrict__ B,                // [64]
    unsigned short* __restrict__ outb,          // [NN][64] bf16
    int nTasks)                                 // NN/8
{
    __shared__ float4 s_w[64 * 33];             // stride 33: 132 f ≡ 4 mod 32 banks
    __shared__ float s_b[64];
    int tid = threadIdx.x;
    for (int idx = tid; idx < 64 * 32; idx += 256) {
        int j = idx >> 5, i4 = idx & 31;
        s_w[j * 33 + i4] = reinterpret_cast<const float4*>(W)[j * 32 + i4];
    }
    if (tid < 64) s_b[tid] = B[tid];
    __syncthreads();

    int wv = __builtin_amdgcn_readfirstlane(tid >> 6);  // provably uniform wave id
    int lane = tid & 63;
    int slot = blockIdx.x * 4 + wv;
    int stride = gridDim.x * 4;
    for (int task = slot; task < nTasks; task += stride) {
        int n0 = task * 8;
        float bb = s_b[lane];
        float acc[8];
#pragma unroll
        for (int r = 0; r < 8; ++r) acc[r] = bb;
        const float4* wrow = &s_w[lane * 33];
        for (int i4 = 0; i4 < 32; ++i4) {
            float4 w4 = wrow[i4];
#pragma unroll
            for (int r = 0; r < 8; ++r) {
                float4 f = featv4[(size_t)(n0 + r) * 32 + i4];  // uniform -> s_load
                acc[r] += w4.x * f.x;
                acc[r] += w4.y * f.y;
                acc[r] += w4.z * f.z;
                acc[r] += w4.w * f.w;
            }
        }
#pragma unroll
        for (int r = 0; r < 8; ++r)
            outb[(size_t)(n0 + r) * 64 + lane] = f2bf(acc[r]);
    }
}

// ---------------------------------------------------------------------------
// K2: layer-1 aggregation. Wave-per-node, lane = dim j (64).
// x2[n][j] = (1/32) * sum_k relu( v1[dst[n,k]][j] + u1[src[n,k]][j]*sp[n,k] )
// Row reads are 128B coalesced (whole wave reads one bf16 row).
// src/dst/sp are wave-uniform -> scalar loads.
// ---------------------------------------------------------------------------
__global__ __launch_bounds__(256) void k_gather1(
    const unsigned short* __restrict__ u1b, const unsigned short* __restrict__ v1b,
    const int* __restrict__ src, const int* __restrict__ dst,
    const float* __restrict__ dists, float* __restrict__ x2)
{
    int tid = threadIdx.x;
    int wv = __builtin_amdgcn_readfirstlane(tid >> 6);
    int lane = tid & 63;
    int slot = blockIdx.x * 4 + wv;
    int stride = gridDim.x * 4;
    for (int n = slot; n < NN; n += stride) {
        float acc = 0.f;
#pragma unroll 4
        for (int k = 0; k < KANCH; ++k) {
            int sk = src[n * KANCH + k];
            int dk = dst[n * KANCH + k];
            float sp = dists[n * KANCH + k];
            float uu = bf2f(u1b[(size_t)sk * 64 + lane]);
            float vv = bf2f(v1b[(size_t)dk * 64 + lane]);
            acc += fmaxf(fmaf(uu, sp, vv), 0.f);
        }
        x2[(size_t)n * 64 + lane] = acc * 0.03125f;
    }
}

// ---------------------------------------------------------------------------
// K2b: layer-2 u/v linears. in=64 (f32 x2), out = u2|v2 concat (lane<32 -> u).
// Same wave-task=8-nodes structure as K1.
// ---------------------------------------------------------------------------
__global__ __launch_bounds__(256) void k_lin64(
    const float4* __restrict__ x2v4,            // [NN*16]
    const float* __restrict__ Wu2, const float* __restrict__ bu2,
    const float* __restrict__ Wv2, const float* __restrict__ bv2,
    unsigned short* __restrict__ u2b, unsigned short* __restrict__ v2b,
    int nTasks)
{
    __shared__ float4 s_w[64 * 17];             // stride 17: 68 f ≡ 4 mod 32 banks
    __shared__ float s_b[64];
    int tid = threadIdx.x;
    for (int idx = tid; idx < 64 * 16; idx += 256) {
        int j = idx >> 4, i4 = idx & 15;
        const float* Wsrc = (j < 32) ? Wu2 : Wv2;
        int jj = j & 31;
        s_w[j * 17 + i4] = reinterpret_cast<const float4*>(Wsrc)[jj * 16 + i4];
    }
    if (tid < 64) s_b[tid] = (tid < 32) ? bu2[tid] : bv2[tid - 32];
    __syncthreads();

    int wv = __builtin_amdgcn_readfirstlane(tid >> 6);
    int lane = tid & 63;
    int slot = blockIdx.x * 4 + wv;
    int stride = gridDim.x * 4;
    for (int task = slot; task < nTasks; task += stride) {
        int n0 = task * 8;
        float bb = s_b[lane];
        float acc[8];
#pragma unroll
        for (int r = 0; r < 8; ++r) acc[r] = bb;
        const float4* wrow = &s_w[lane * 17];
        for (int i4 = 0; i4 < 16; ++i4) {
            float4 w4 = wrow[i4];
#pragma unroll
            for (int r = 0; r < 8; ++r) {
                float4 f = x2v4[(size_t)(n0 + r) * 16 + i4];
                acc[r] += w4.x * f.x;
                acc[r] += w4.y * f.y;
                acc[r] += w4.z * f.z;
                acc[r] += w4.w * f.w;
            }
        }
#pragma unroll
        for (int r = 0; r < 8; ++r) {
            unsigned short val = f2bf(acc[r]);
            if (lane < 32) u2b[(size_t)(n0 + r) * 32 + lane] = val;
            else           v2b[(size_t)(n0 + r) * 32 + (lane - 32)] = val;
        }
    }
}

// ---------------------------------------------------------------------------
// K3: layer-2 message + position dot + L2 normalize.
// Lane = edge (wave covers 2 nodes x 32 edges). Each lane pulls both 64B
// bf16 rows into regs (4x uint4 each), does the 32-dim dot in-lane,
// then one 5-step shfl_xor reduce per half-wave for the norm.
// ---------------------------------------------------------------------------
__global__ __launch_bounds__(256) void k_out(
    const unsigned short* __restrict__ u2b, const unsigned short* __restrict__ v2b,
    const int* __restrict__ src, const int* __restrict__ dst,
    const float* __restrict__ dists, const float* __restrict__ wp2,
    const float* __restrict__ bp2, float* __restrict__ out)
{
    int tid = threadIdx.x;
    int wv = __builtin_amdgcn_readfirstlane(tid >> 6);
    int lane = tid & 63;
    int slot = blockIdx.x * 4 + wv;
    int stride = gridDim.x * 4;
    float bp = bp2[0];
    const int nTasks = NN / 2;   // 2 nodes per wave
    for (int task = slot; task < nTasks; task += stride) {
        int e = task * 64 + lane;          // edge id: node = e>>5, k = e&31
        int s = src[e], d = dst[e];
        float sp = dists[e];
        const uint4* urow = reinterpret_cast<const uint4*>(u2b) + (size_t)s * 4;
        const uint4* vrow = reinterpret_cast<const uint4*>(v2b) + (size_t)d * 4;
        uint4 u0 = urow[0], u1 = urow[1], u2 = urow[2], u3 = urow[3];
        uint4 v0 = vrow[0], v1 = vrow[1], v2 = vrow[2], v3 = vrow[3];
        float p0 = 0.f, p1 = 0.f;
#define DOT2(UW, VW, C0)                                              \
        {                                                             \
            float ua = __uint_as_float((UW) << 16);                   \
            float ub = __uint_as_float((UW) & 0xFFFF0000u);           \
            float va = __uint_as_float((VW) << 16);                   \
            float vb = __uint_as_float((VW) & 0xFFFF0000u);           \
            float ma = fmaxf(fmaf(ua, sp, va), 0.f);                  \
            float mb = fmaxf(fmaf(ub, sp, vb), 0.f);                  \
            p0 = fmaf(ma, wp2[(C0)], p0);                             \
            p1 = fmaf(mb, wp2[(C0) + 1], p1);                         \
        }
        DOT2(u0.x, v0.x, 0)  DOT2(u0.y, v0.y, 2)  DOT2(u0.z, v0.z, 4)  DOT2(u0.w, v0.w, 6)
        DOT2(u1.x, v1.x, 8)  DOT2(u1.y, v1.y, 10) DOT2(u1.z, v1.z, 12) DOT2(u1.w, v1.w, 14)
        DOT2(u2.x, v2.x, 16) DOT2(u2.y, v2.y, 18) DOT2(u2.z, v2.z, 20) DOT2(u2.w, v2.w, 22)
        DOT2(u3.x, v3.x, 24) DOT2(u3.y, v3.y, 26) DOT2(u3.z, v3.z, 28) DOT2(u3.w, v3.w, 30)
#undef DOT2
        float q = p0 + p1 + bp;
        float s2 = q * q;
#pragma unroll
        for (int off = 16; off >= 1; off >>= 1)
            s2 += __shfl_xor(s2, off);     // stays within each 32-lane half
        float nrm = sqrtf(s2);
        float den = fmaxf(nrm, 1e-12f);
        out[(size_t)task * 64 + lane] = q / den;
    }
}

// ---------------------------------------------------------------------------
extern "C" void kernel_launch(void* const* d_in, const int* in_sizes, int n_in,
                              void* d_out, int out_size, void* d_ws, size_t ws_size,
                              hipStream_t stream)
{
    const float* feat  = (const float*)d_in[0];
    const float* dists = (const float*)d_in[1];
    const int*   src   = (const int*)d_in[2];
    const int*   dst   = (const int*)d_in[3];
    const float* w_pre = (const float*)d_in[4];
    const float* b_pre = (const float*)d_in[5];
    const float* Wu1   = (const float*)d_in[6];
    const float* bu1   = (const float*)d_in[7];
    const float* Wv1   = (const float*)d_in[8];
    const float* bv1   = (const float*)d_in[9];
    // d_in[10]=wp1, d_in[11]=bp1: layer-1 position output is discarded
    const float* Wu2   = (const float*)d_in[12];
    const float* bu2   = (const float*)d_in[13];
    const float* Wv2   = (const float*)d_in[14];
    const float* bv2   = (const float*)d_in[15];
    const float* wp2   = (const float*)d_in[16];
    const float* bp2   = (const float*)d_in[17];
    float* out = (float*)d_out;

    // workspace layout (~25.7 MB): composed weights | x2 f32 | bf16 tables
    float* wu_eff = (float*)d_ws;                       // 8192 f
    float* wv_eff = wu_eff + 8192;                      // 8192 f
    float* bu_eff = wv_eff + 8192;                      // 64
    float* bv_eff = bu_eff + 64;                        // 64
    float* x2     = bv_eff + 64;                        // NN*64 f32
    unsigned short* u1b = (unsigned short*)(x2 + (size_t)NN * 64);  // NN*64 bf16
    unsigned short* v1b = u1b + (size_t)NN * 64;                    // NN*64 bf16
    unsigned short* u2b = u1b;                          // alias: u1b dead after K2
    unsigned short* v2b = v1b;                          // alias: v1b dead after K2

    k_combine<<<65, 256, 0, stream>>>(w_pre, b_pre, Wu1, bu1, Wv1, bv1,
                                      wu_eff, wv_eff, bu_eff, bv_eff);
    k_lin128<<<512, 256, 0, stream>>>((const float4*)feat, wu_eff, bu_eff, u1b, NN / 8);
    k_lin128<<<512, 256, 0, stream>>>((const float4*)feat, wv_eff, bv_eff, v1b, NN / 8);
    k_gather1<<<2048, 256, 0, stream>>>(u1b, v1b, src, dst, dists, x2);
    k_lin64<<<512, 256, 0, stream>>>((const float4*)x2, Wu2, bu2, Wv2, bv2,
                                     u2b, v2b, NN / 8);
    k_out<<<2048, 256, 0, stream>>>(u2b, v2b, src, dst, dists, wp2, bp2, out);
}

// Round 2
// 235.543 us; speedup vs baseline: 1.1870x; 1.1870x over previous
//
#include <hip/hip_runtime.h>

// PGNN: N=50000 nodes, K=32 anchors/edges per node, E=1.6M edges
// out: normalize(out_position)[N,32] f32
constexpr int NN = 50000;
constexpr int KANCH = 32;

static __device__ __forceinline__ float bf2f(unsigned short u) {
    return __uint_as_float(((unsigned int)u) << 16);
}
static __device__ __forceinline__ unsigned short f2bf(float f) {
    unsigned int x = __float_as_uint(f);
    x += 0x7FFFu + ((x >> 16) & 1u);   // round-to-nearest-even
    return (unsigned short)(x >> 16);
}

// ---------------------------------------------------------------------------
// K0: compose layer-1 weights through the pre-linear.
// wu_eff = Wu1 @ w_pre  [64,128];  bu_eff = Wu1 @ b_pre + bu1  [64]
// ---------------------------------------------------------------------------
__global__ __launch_bounds__(256) void k_combine(
    const float* __restrict__ w_pre, const float* __restrict__ b_pre,
    const float* __restrict__ Wu1, const float* __restrict__ bu1,
    const float* __restrict__ Wv1, const float* __restrict__ bv1,
    float* __restrict__ wu_eff, float* __restrict__ wv_eff,
    float* __restrict__ bu_eff, float* __restrict__ bv_eff)
{
    int gid = blockIdx.x * 256 + threadIdx.x;
    if (gid < 8192) {
        int j = gid >> 7, i = gid & 127;
        float a = 0.f;
        for (int t = 0; t < 64; ++t) a += Wu1[j * 64 + t] * w_pre[t * 128 + i];
        wu_eff[gid] = a;
    } else if (gid < 16384) {
        int g = gid - 8192;
        int j = g >> 7, i = g & 127;
        float a = 0.f;
        for (int t = 0; t < 64; ++t) a += Wv1[j * 64 + t] * w_pre[t * 128 + i];
        wv_eff[g] = a;
    } else if (gid < 16448) {
        int j = gid - 16384;
        float a = bu1[j];
        for (int t = 0; t < 64; ++t) a += Wu1[j * 64 + t] * b_pre[t];
        bu_eff[j] = a;
    } else if (gid < 16512) {
        int j = gid - 16448;
        float a = bv1[j];
        for (int t = 0; t < 64; ++t) a += Wv1[j * 64 + t] * b_pre[t];
        bv_eff[j] = a;
    }
}

// ---------------------------------------------------------------------------
// K1: fused u1/v1 linears. in=128 (feat f32), out=2x64 bf16 tables.
// Wave-task = 8 nodes; lane = output dim j. Both weight sets in LDS
// (float4 stride 33: 2-way phase conflict only). feat rows are wave-uniform
// -> scalar loads; feat is read ONCE for both tables.
// ---------------------------------------------------------------------------
__global__ __launch_bounds__(256) void k_lin128_uv(
    const float4* __restrict__ featv4,          // [NN*32]
    const float* __restrict__ Wu, const float* __restrict__ Bu,
    const float* __restrict__ Wv, const float* __restrict__ Bv,
    unsigned short* __restrict__ ub,            // [NN][64] bf16
    unsigned short* __restrict__ vb,            // [NN][64] bf16
    int nTasks)                                 // NN/8
{
    __shared__ float4 s_wu[64 * 33];
    __shared__ float4 s_wv[64 * 33];
    __shared__ float s_bu[64], s_bv[64];
    int tid = threadIdx.x;
    for (int idx = tid; idx < 64 * 32; idx += 256) {
        int j = idx >> 5, i4 = idx & 31;
        s_wu[j * 33 + i4] = reinterpret_cast<const float4*>(Wu)[j * 32 + i4];
        s_wv[j * 33 + i4] = reinterpret_cast<const float4*>(Wv)[j * 32 + i4];
    }
    if (tid < 64) { s_bu[tid] = Bu[tid]; s_bv[tid] = Bv[tid]; }
    __syncthreads();

    int wv = __builtin_amdgcn_readfirstlane(tid >> 6);
    int lane = tid & 63;
    int slot = blockIdx.x * 4 + wv;
    int stride = gridDim.x * 4;
    for (int task = slot; task < nTasks; task += stride) {
        int n0 = task * 8;
        float bu = s_bu[lane], bv = s_bv[lane];
        float au[8], av[8];
#pragma unroll
        for (int r = 0; r < 8; ++r) { au[r] = bu; av[r] = bv; }
        const float4* wur = &s_wu[lane * 33];
        const float4* wvr = &s_wv[lane * 33];
        for (int i4 = 0; i4 < 32; ++i4) {
            float4 wu4 = wur[i4];
            float4 wv4 = wvr[i4];
#pragma unroll
            for (int r = 0; r < 8; ++r) {
                float4 f = featv4[(size_t)(n0 + r) * 32 + i4];  // uniform -> s_load
                au[r] += wu4.x * f.x; av[r] += wv4.x * f.x;
                au[r] += wu4.y * f.y; av[r] += wv4.y * f.y;
                au[r] += wu4.z * f.z; av[r] += wv4.z * f.z;
                au[r] += wu4.w * f.w; av[r] += wv4.w * f.w;
            }
        }
#pragma unroll
        for (int r = 0; r < 8; ++r) {
            ub[(size_t)(n0 + r) * 64 + lane] = f2bf(au[r]);
            vb[(size_t)(n0 + r) * 64 + lane] = f2bf(av[r]);
        }
    }
}

// ---------------------------------------------------------------------------
// K2: layer-1 aggregation. Wave-per-node; lane = (edge-subgroup es=lane>>4,
// chunk c=lane&15). Each table read is ushort4 (8B/lane): the wave covers
// 4 rows x 128B = 512B per instruction, coalesced within rows.
// x2[n][j] = (1/32) * sum_k relu( v1[dst][j] + u1[src][j]*sp )
// ---------------------------------------------------------------------------
__global__ __launch_bounds__(256) void k_gather1(
    const ushort4* __restrict__ u1v, const ushort4* __restrict__ v1v,
    const int* __restrict__ src, const int* __restrict__ dst,
    const float* __restrict__ dists, float4* __restrict__ x2v4)
{
    int tid = threadIdx.x;
    int wv = __builtin_amdgcn_readfirstlane(tid >> 6);
    int lane = tid & 63;
    int c = lane & 15;      // dims 4c..4c+3
    int es = lane >> 4;     // edge subgroup 0..3
    int slot = blockIdx.x * 4 + wv;
    int stride = gridDim.x * 4;
    for (int n = slot; n < NN; n += stride) {
        int base = n * KANCH;
        float a0 = 0.f, a1 = 0.f, a2 = 0.f, a3 = 0.f;
#pragma unroll
        for (int kk = 0; kk < 8; ++kk) {
            int k = kk * 4 + es;
            int sk = src[base + k];
            int dk = dst[base + k];
            float sp = dists[base + k];
            ushort4 uu = u1v[(size_t)sk * 16 + c];
            ushort4 vv = v1v[(size_t)dk * 16 + c];
            a0 += fmaxf(fmaf(bf2f(uu.x), sp, bf2f(vv.x)), 0.f);
            a1 += fmaxf(fmaf(bf2f(uu.y), sp, bf2f(vv.y)), 0.f);
            a2 += fmaxf(fmaf(bf2f(uu.z), sp, bf2f(vv.z)), 0.f);
            a3 += fmaxf(fmaf(bf2f(uu.w), sp, bf2f(vv.w)), 0.f);
        }
        // reduce the 4 edge-subgroups (lanes ^16, ^32)
        a0 += __shfl_xor(a0, 16); a0 += __shfl_xor(a0, 32);
        a1 += __shfl_xor(a1, 16); a1 += __shfl_xor(a1, 32);
        a2 += __shfl_xor(a2, 16); a2 += __shfl_xor(a2, 32);
        a3 += __shfl_xor(a3, 16); a3 += __shfl_xor(a3, 32);
        if (lane < 16) {
            float4 r;
            r.x = a0 * 0.03125f; r.y = a1 * 0.03125f;
            r.z = a2 * 0.03125f; r.w = a3 * 0.03125f;
            x2v4[(size_t)n * 16 + c] = r;
        }
    }
}

// ---------------------------------------------------------------------------
// K2b: layer-2 u/v linears. in=64 (f32 x2), out = u2|v2 concat (lane<32 -> u).
// ---------------------------------------------------------------------------
__global__ __launch_bounds__(256) void k_lin64(
    const float4* __restrict__ x2v4,            // [NN*16]
    const float* __restrict__ Wu2, const float* __restrict__ bu2,
    const float* __restrict__ Wv2, const float* __restrict__ bv2,
    unsigned short* __restrict__ u2b, unsigned short* __restrict__ v2b,
    int nTasks)
{
    __shared__ float4 s_w[64 * 17];
    __shared__ float s_b[64];
    int tid = threadIdx.x;
    for (int idx = tid; idx < 64 * 16; idx += 256) {
        int j = idx >> 4, i4 = idx & 15;
        const float* Wsrc = (j < 32) ? Wu2 : Wv2;
        int jj = j & 31;
        s_w[j * 17 + i4] = reinterpret_cast<const float4*>(Wsrc)[jj * 16 + i4];
    }
    if (tid < 64) s_b[tid] = (tid < 32) ? bu2[tid] : bv2[tid - 32];
    __syncthreads();

    int wv = __builtin_amdgcn_readfirstlane(tid >> 6);
    int lane = tid & 63;
    int slot = blockIdx.x * 4 + wv;
    int stride = gridDim.x * 4;
    for (int task = slot; task < nTasks; task += stride) {
        int n0 = task * 8;
        float bb = s_b[lane];
        float acc[8];
#pragma unroll
        for (int r = 0; r < 8; ++r) acc[r] = bb;
        const float4* wrow = &s_w[lane * 17];
        for (int i4 = 0; i4 < 16; ++i4) {
            float4 w4 = wrow[i4];
#pragma unroll
            for (int r = 0; r < 8; ++r) {
                float4 f = x2v4[(size_t)(n0 + r) * 16 + i4];
                acc[r] += w4.x * f.x;
                acc[r] += w4.y * f.y;
                acc[r] += w4.z * f.z;
                acc[r] += w4.w * f.w;
            }
        }
#pragma unroll
        for (int r = 0; r < 8; ++r) {
            unsigned short val = f2bf(acc[r]);
            if (lane < 32) u2b[(size_t)(n0 + r) * 32 + lane] = val;
            else           v2b[(size_t)(n0 + r) * 32 + (lane - 32)] = val;
        }
    }
}

// ---------------------------------------------------------------------------
// K3: layer-2 message + position dot + L2 normalize. Wave-per-node.
// lane = (edge-subgroup es=lane>>3, chunk c=lane&7). Table reads are ushort4
// (8B/lane): wave covers 8 rows x 64B = 512B per instruction, coalesced.
// Per-edge dot via 3 shfl_xor; q-collection via 4 indexed shfls (no LDS);
// norm via 5 shfl_xor within each 32-lane half.
// ---------------------------------------------------------------------------
__global__ __launch_bounds__(256) void k_out(
    const ushort4* __restrict__ u2v, const ushort4* __restrict__ v2v,
    const int* __restrict__ src, const int* __restrict__ dst,
    const float* __restrict__ dists, const float* __restrict__ wp2,
    const float* __restrict__ bp2, float* __restrict__ out)
{
    int tid = threadIdx.x;
    int wv = __builtin_amdgcn_readfirstlane(tid >> 6);
    int lane = tid & 63;
    int c = lane & 7;       // dims 4c..4c+3
    int es = lane >> 3;     // edge subgroup 0..7
    int slot = blockIdx.x * 4 + wv;
    int stride = gridDim.x * 4;
    float4 w4 = reinterpret_cast<const float4*>(wp2)[c];  // wp2[4c..4c+3]
    float bp = bp2[0];
    for (int n = slot; n < NN; n += stride) {
        int base = n * KANCH;
        float q0, q1, q2, q3;
#pragma unroll
        for (int kk = 0; kk < 4; ++kk) {
            int k = kk * 8 + es;
            int sk = src[base + k];
            int dk = dst[base + k];
            float sp = dists[base + k];
            ushort4 uu = u2v[(size_t)sk * 8 + c];
            ushort4 vv = v2v[(size_t)dk * 8 + c];
            float p;
            p  = fmaxf(fmaf(bf2f(uu.x), sp, bf2f(vv.x)), 0.f) * w4.x;
            p += fmaxf(fmaf(bf2f(uu.y), sp, bf2f(vv.y)), 0.f) * w4.y;
            p += fmaxf(fmaf(bf2f(uu.z), sp, bf2f(vv.z)), 0.f) * w4.z;
            p += fmaxf(fmaf(bf2f(uu.w), sp, bf2f(vv.w)), 0.f) * w4.w;
            // butterfly over the 8-lane chunk group -> all 8 lanes hold dot_k
            p += __shfl_xor(p, 1);
            p += __shfl_xor(p, 2);
            p += __shfl_xor(p, 4);
            if (kk == 0) q0 = p; else if (kk == 1) q1 = p;
            else if (kk == 2) q2 = p; else q3 = p;
        }
        // lane t (0..31) wants q for edge t: iter t>>3, from lane (t&7)*8
        int srcl = (lane & 7) * 8;
        float s0 = __shfl(q0, srcl);
        float s1 = __shfl(q1, srcl);
        float s2_ = __shfl(q2, srcl);
        float s3 = __shfl(q3, srcl);
        int it = (lane >> 3) & 3;
        float q = (it == 0) ? s0 : (it == 1) ? s1 : (it == 2) ? s2_ : s3;
        q += bp;
        float ss = q * q;
#pragma unroll
        for (int off = 16; off >= 1; off >>= 1)
            ss += __shfl_xor(ss, off);     // stays within each 32-lane half
        float den = fmaxf(sqrtf(ss), 1e-12f);
        if (lane < 32) out[(size_t)n * KANCH + lane] = q / den;
    }
}

// ---------------------------------------------------------------------------
extern "C" void kernel_launch(void* const* d_in, const int* in_sizes, int n_in,
                              void* d_out, int out_size, void* d_ws, size_t ws_size,
                              hipStream_t stream)
{
    const float* feat  = (const float*)d_in[0];
    const float* dists = (const float*)d_in[1];
    const int*   src   = (const int*)d_in[2];
    const int*   dst   = (const int*)d_in[3];
    const float* w_pre = (const float*)d_in[4];
    const float* b_pre = (const float*)d_in[5];
    const float* Wu1   = (const float*)d_in[6];
    const float* bu1   = (const float*)d_in[7];
    const float* Wv1   = (const float*)d_in[8];
    const float* bv1   = (const float*)d_in[9];
    // d_in[10]=wp1, d_in[11]=bp1: layer-1 position output is discarded
    const float* Wu2   = (const float*)d_in[12];
    const float* bu2   = (const float*)d_in[13];
    const float* Wv2   = (const float*)d_in[14];
    const float* bv2   = (const float*)d_in[15];
    const float* wp2   = (const float*)d_in[16];
    const float* bp2   = (const float*)d_in[17];
    float* out = (float*)d_out;

    // workspace layout (~25.7 MB): composed weights | x2 f32 | bf16 tables
    float* wu_eff = (float*)d_ws;                       // 8192 f
    float* wv_eff = wu_eff + 8192;                      // 8192 f
    float* bu_eff = wv_eff + 8192;                      // 64
    float* bv_eff = bu_eff + 64;                        // 64
    float* x2     = bv_eff + 64;                        // NN*64 f32
    unsigned short* u1b = (unsigned short*)(x2 + (size_t)NN * 64);  // NN*64 bf16
    unsigned short* v1b = u1b + (size_t)NN * 64;                    // NN*64 bf16
    unsigned short* u2b = u1b;                          // alias: u1b dead after K2
    unsigned short* v2b = v1b;                          // alias: v1b dead after K2

    k_combine<<<65, 256, 0, stream>>>(w_pre, b_pre, Wu1, bu1, Wv1, bv1,
                                      wu_eff, wv_eff, bu_eff, bv_eff);
    k_lin128_uv<<<512, 256, 0, stream>>>((const float4*)feat, wu_eff, bu_eff,
                                         wv_eff, bv_eff, u1b, v1b, NN / 8);
    k_gather1<<<2048, 256, 0, stream>>>((const ushort4*)u1b, (const ushort4*)v1b,
                                        src, dst, dists, (float4*)x2);
    k_lin64<<<512, 256, 0, stream>>>((const float4*)x2, Wu2, bu2, Wv2, bv2,
                                     u2b, v2b, NN / 8);
    k_out<<<2048, 256, 0, stream>>>((const ushort4*)u2b, (const ushort4*)v2b,
                                    src, dst, dists, wp2, bp2, out);
}

// Round 3
// 108.772 us; speedup vs baseline: 2.5703x; 2.1655x over previous
//
#include <hip/hip_runtime.h>

// PGNN: N=50000 nodes, K=32 anchors/edges per node, E=1.6M edges
// out: normalize(out_position)[N,32] f32
constexpr int NN = 50000;
constexpr int KANCH = 32;

typedef __attribute__((ext_vector_type(8))) short bfrag;   // 8 bf16 (4 VGPR)
typedef __attribute__((ext_vector_type(4))) float ffrag;   // 4 f32 acc

static __device__ __forceinline__ float bf2f(unsigned short u) {
    return __uint_as_float(((unsigned int)u) << 16);
}
static __device__ __forceinline__ unsigned short f2bf(float f) {
    unsigned int x = __float_as_uint(f);
    x += 0x7FFFu + ((x >> 16) & 1u);   // round-to-nearest-even
    return (unsigned short)(x >> 16);
}

// ---------------------------------------------------------------------------
// K0: compose layer-1 weights through the pre-linear and pack all weights
// to bf16 MFMA tables.  wcat1[j][i] = bf16( (Wu1|Wv1) @ w_pre )  [128][128]
// bias1[j] = (Wu1|Wv1)@b_pre + (bu1|bv1)   (f32)
// wcat2[j][i] = bf16( Wu2|Wv2 )  [64][64];  bias2 = bu2|bv2 (f32)
// ---------------------------------------------------------------------------
__global__ __launch_bounds__(256) void k_prep(
    const float* __restrict__ w_pre, const float* __restrict__ b_pre,
    const float* __restrict__ Wu1, const float* __restrict__ bu1,
    const float* __restrict__ Wv1, const float* __restrict__ bv1,
    const float* __restrict__ Wu2, const float* __restrict__ bu2,
    const float* __restrict__ Wv2, const float* __restrict__ bv2,
    unsigned short* __restrict__ wcat1, float* __restrict__ bias1,
    unsigned short* __restrict__ wcat2, float* __restrict__ bias2)
{
    int gid = blockIdx.x * 256 + threadIdx.x;
    if (gid < 16384) {
        int j = gid >> 7, i = gid & 127;
        const float* Wr = (j < 64) ? (Wu1 + j * 64) : (Wv1 + (j - 64) * 64);
        float a = 0.f;
        for (int t = 0; t < 64; ++t) a += Wr[t] * w_pre[t * 128 + i];
        wcat1[gid] = f2bf(a);
    } else if (gid < 16384 + 4096) {
        int g = gid - 16384;
        int j = g >> 6, i = g & 63;
        float w = (j < 32) ? Wu2[j * 64 + i] : Wv2[(j - 32) * 64 + i];
        wcat2[g] = f2bf(w);
    } else if (gid < 16384 + 4096 + 128) {
        int j = gid - (16384 + 4096);
        const float* Wr = (j < 64) ? (Wu1 + j * 64) : (Wv1 + (j - 64) * 64);
        float a = (j < 64) ? bu1[j] : bv1[j - 64];
        for (int t = 0; t < 64; ++t) a += Wr[t] * b_pre[t];
        bias1[j] = a;
    } else if (gid < 16384 + 4096 + 128 + 64) {
        int j = gid - (16384 + 4096 + 128);
        bias2[j] = (j < 32) ? bu2[j] : bv2[j - 32];
    }
}

// ---------------------------------------------------------------------------
// K1: layer-1 u/v linears via MFMA.  D[node][out128] = feat[50000,128] @ Wᵀ.
// Wave-task = 16-node tile; 8 out-tiles of 16; K=128 (4 MFMA K-steps).
// A (feat f32) loaded from global, split in-register into bf16 hi+lo
// (f = hi + lo exactly -> no input-quantization error; 2 MFMAs per step).
// W in LDS bf16, row stride 272 B (2-way bank alias only).
// ---------------------------------------------------------------------------
__global__ __launch_bounds__(256) void k_gemm1(
    const float* __restrict__ feat,            // [NN][128]
    const unsigned short* __restrict__ wcat,   // [128][128] bf16
    const float* __restrict__ bias,            // [128] f32
    unsigned short* __restrict__ ub,           // [NN][64] bf16
    unsigned short* __restrict__ vb,           // [NN][64] bf16
    int nTiles)                                // NN/16
{
    __shared__ unsigned short s_w[128 * 136];  // 136 us = 272 B row stride
    __shared__ float s_b[128];
    int tid = threadIdx.x;
    for (int idx = tid; idx < 128 * 16; idx += 256) {      // 16B chunks
        int r = idx >> 4, c8 = idx & 15;
        const uint4* g = reinterpret_cast<const uint4*>(wcat + r * 128 + c8 * 8);
        *reinterpret_cast<uint4*>(&s_w[r * 136 + c8 * 8]) = *g;
    }
    if (tid < 128) s_b[tid] = bias[tid];
    __syncthreads();

    int wv = __builtin_amdgcn_readfirstlane(tid >> 6);
    int lane = tid & 63;
    int col = lane & 15;        // A row (node) / D col (out) / W row
    int grp = lane >> 4;        // k-subchunk 0..3
    int slot = blockIdx.x * 4 + wv;
    int stride = gridDim.x * 4;
    for (int tile = slot; tile < nTiles; tile += stride) {
        int n0 = tile * 16;
        const float* fp = feat + (size_t)(n0 + col) * 128 + grp * 8;
        bfrag AH[4], AL[4];
#pragma unroll
        for (int s = 0; s < 4; ++s) {
            float4 p0 = *reinterpret_cast<const float4*>(fp + s * 32);
            float4 p1 = *reinterpret_cast<const float4*>(fp + s * 32 + 4);
            float a8[8] = {p0.x, p0.y, p0.z, p0.w, p1.x, p1.y, p1.z, p1.w};
#pragma unroll
            for (int e = 0; e < 8; ++e) {
                unsigned short hb = f2bf(a8[e]);
                AH[s][e] = (short)hb;
                AL[s][e] = (short)f2bf(a8[e] - bf2f(hb));
            }
        }
#pragma unroll
        for (int t = 0; t < 8; ++t) {
            ffrag a = {0.f, 0.f, 0.f, 0.f};
#pragma unroll
            for (int s = 0; s < 4; ++s) {
                const bfrag w = *reinterpret_cast<const bfrag*>(
                    &s_w[(t * 16 + col) * 136 + s * 32 + grp * 8]);
                a = __builtin_amdgcn_mfma_f32_16x16x32_bf16(AH[s], w, a, 0, 0, 0);
                a = __builtin_amdgcn_mfma_f32_16x16x32_bf16(AL[s], w, a, 0, 0, 0);
            }
            float bb = s_b[t * 16 + col];
#pragma unroll
            for (int j = 0; j < 4; ++j) {
                int node = n0 + grp * 4 + j;
                unsigned short o = f2bf(a[j] + bb);
                if (t < 4) ub[(size_t)node * 64 + t * 16 + col] = o;
                else       vb[(size_t)node * 64 + (t - 4) * 16 + col] = o;
            }
        }
    }
}

// ---------------------------------------------------------------------------
// K2: layer-1 aggregation. Wave-per-node; lane = (edge-subgroup es=lane>>4,
// chunk c=lane&15). Each table read is ushort4 (8B/lane): wave covers
// 4 rows x 128B = 512B per instruction. Output x2 written directly as bf16.
// ---------------------------------------------------------------------------
__global__ __launch_bounds__(256) void k_gather1(
    const ushort4* __restrict__ u1v, const ushort4* __restrict__ v1v,
    const int* __restrict__ src, const int* __restrict__ dst,
    const float* __restrict__ dists, ushort4* __restrict__ x2v)
{
    int tid = threadIdx.x;
    int wv = __builtin_amdgcn_readfirstlane(tid >> 6);
    int lane = tid & 63;
    int c = lane & 15;      // dims 4c..4c+3
    int es = lane >> 4;     // edge subgroup 0..3
    int slot = blockIdx.x * 4 + wv;
    int stride = gridDim.x * 4;
    for (int n = slot; n < NN; n += stride) {
        int base = n * KANCH;
        float a0 = 0.f, a1 = 0.f, a2 = 0.f, a3 = 0.f;
#pragma unroll
        for (int kk = 0; kk < 8; ++kk) {
            int k = kk * 4 + es;
            int sk = src[base + k];
            int dk = dst[base + k];
            float sp = dists[base + k];
            ushort4 uu = u1v[(size_t)sk * 16 + c];
            ushort4 vv = v1v[(size_t)dk * 16 + c];
            a0 += fmaxf(fmaf(bf2f(uu.x), sp, bf2f(vv.x)), 0.f);
            a1 += fmaxf(fmaf(bf2f(uu.y), sp, bf2f(vv.y)), 0.f);
            a2 += fmaxf(fmaf(bf2f(uu.z), sp, bf2f(vv.z)), 0.f);
            a3 += fmaxf(fmaf(bf2f(uu.w), sp, bf2f(vv.w)), 0.f);
        }
        a0 += __shfl_xor(a0, 16); a0 += __shfl_xor(a0, 32);
        a1 += __shfl_xor(a1, 16); a1 += __shfl_xor(a1, 32);
        a2 += __shfl_xor(a2, 16); a2 += __shfl_xor(a2, 32);
        a3 += __shfl_xor(a3, 16); a3 += __shfl_xor(a3, 32);
        if (lane < 16) {
            ushort4 r;
            r.x = f2bf(a0 * 0.03125f); r.y = f2bf(a1 * 0.03125f);
            r.z = f2bf(a2 * 0.03125f); r.w = f2bf(a3 * 0.03125f);
            x2v[(size_t)n * 16 + c] = r;
        }
    }
}

// ---------------------------------------------------------------------------
// K3: layer-2 u/v linears via MFMA.  [50000,64] bf16 @ [64,64]ᵀ bf16.
// Same structure as k_gemm1; A is already bf16 (direct dwordx4 loads),
// K=64 (2 steps), 4 out-tiles. W row stride 144 B.
// ---------------------------------------------------------------------------
__global__ __launch_bounds__(256) void k_gemm2(
    const unsigned short* __restrict__ x2b,    // [NN][64] bf16
    const unsigned short* __restrict__ wcat,   // [64][64] bf16
    const float* __restrict__ bias,            // [64] f32
    unsigned short* __restrict__ ub,           // [NN][32] bf16
    unsigned short* __restrict__ vb,           // [NN][32] bf16
    int nTiles)
{
    __shared__ unsigned short s_w[64 * 72];    // 72 us = 144 B row stride
    __shared__ float s_b[64];
    int tid = threadIdx.x;
    for (int idx = tid; idx < 64 * 8; idx += 256) {
        int r = idx >> 3, c8 = idx & 7;
        const uint4* g = reinterpret_cast<const uint4*>(wcat + r * 64 + c8 * 8);
        *reinterpret_cast<uint4*>(&s_w[r * 72 + c8 * 8]) = *g;
    }
    if (tid < 64) s_b[tid] = bias[tid];
    __syncthreads();

    int wv = __builtin_amdgcn_readfirstlane(tid >> 6);
    int lane = tid & 63;
    int col = lane & 15;
    int grp = lane >> 4;
    int slot = blockIdx.x * 4 + wv;
    int stride = gridDim.x * 4;
    for (int tile = slot; tile < nTiles; tile += stride) {
        int n0 = tile * 16;
        bfrag A[2];
#pragma unroll
        for (int s = 0; s < 2; ++s) {
            uint4 raw = *reinterpret_cast<const uint4*>(
                x2b + (size_t)(n0 + col) * 64 + s * 32 + grp * 8);
            A[s] = *reinterpret_cast<const bfrag*>(&raw);
        }
#pragma unroll
        for (int t = 0; t < 4; ++t) {
            ffrag a = {0.f, 0.f, 0.f, 0.f};
#pragma unroll
            for (int s = 0; s < 2; ++s) {
                const bfrag w = *reinterpret_cast<const bfrag*>(
                    &s_w[(t * 16 + col) * 72 + s * 32 + grp * 8]);
                a = __builtin_amdgcn_mfma_f32_16x16x32_bf16(A[s], w, a, 0, 0, 0);
            }
            float bb = s_b[t * 16 + col];
#pragma unroll
            for (int j = 0; j < 4; ++j) {
                int node = n0 + grp * 4 + j;
                unsigned short o = f2bf(a[j] + bb);
                if (t < 2) ub[(size_t)node * 32 + t * 16 + col] = o;
                else       vb[(size_t)node * 32 + (t - 2) * 16 + col] = o;
            }
        }
    }
}

// ---------------------------------------------------------------------------
// K4: layer-2 message + position dot + L2 normalize. Wave-per-node.
// lane = (edge-subgroup es=lane>>3, chunk c=lane&7). ushort4 table reads;
// per-edge dot via 3 shfl_xor; q-collection via indexed shfls; 5-shfl norm.
// ---------------------------------------------------------------------------
__global__ __launch_bounds__(256) void k_out(
    const ushort4* __restrict__ u2v, const ushort4* __restrict__ v2v,
    const int* __restrict__ src, const int* __restrict__ dst,
    const float* __restrict__ dists, const float* __restrict__ wp2,
    const float* __restrict__ bp2, float* __restrict__ out)
{
    int tid = threadIdx.x;
    int wv = __builtin_amdgcn_readfirstlane(tid >> 6);
    int lane = tid & 63;
    int c = lane & 7;       // dims 4c..4c+3
    int es = lane >> 3;     // edge subgroup 0..7
    int slot = blockIdx.x * 4 + wv;
    int stride = gridDim.x * 4;
    float4 w4 = reinterpret_cast<const float4*>(wp2)[c];
    float bp = bp2[0];
    for (int n = slot; n < NN; n += stride) {
        int base = n * KANCH;
        float q0, q1, q2, q3;
#pragma unroll
        for (int kk = 0; kk < 4; ++kk) {
            int k = kk * 8 + es;
            int sk = src[base + k];
            int dk = dst[base + k];
            float sp = dists[base + k];
            ushort4 uu = u2v[(size_t)sk * 8 + c];
            ushort4 vv = v2v[(size_t)dk * 8 + c];
            float p;
            p  = fmaxf(fmaf(bf2f(uu.x), sp, bf2f(vv.x)), 0.f) * w4.x;
            p += fmaxf(fmaf(bf2f(uu.y), sp, bf2f(vv.y)), 0.f) * w4.y;
            p += fmaxf(fmaf(bf2f(uu.z), sp, bf2f(vv.z)), 0.f) * w4.z;
            p += fmaxf(fmaf(bf2f(uu.w), sp, bf2f(vv.w)), 0.f) * w4.w;
            p += __shfl_xor(p, 1);
            p += __shfl_xor(p, 2);
            p += __shfl_xor(p, 4);
            if (kk == 0) q0 = p; else if (kk == 1) q1 = p;
            else if (kk == 2) q2 = p; else q3 = p;
        }
        int srcl = (lane & 7) * 8;
        float s0 = __shfl(q0, srcl);
        float s1 = __shfl(q1, srcl);
        float s2_ = __shfl(q2, srcl);
        float s3 = __shfl(q3, srcl);
        int it = (lane >> 3) & 3;
        float q = (it == 0) ? s0 : (it == 1) ? s1 : (it == 2) ? s2_ : s3;
        q += bp;
        float ss = q * q;
#pragma unroll
        for (int off = 16; off >= 1; off >>= 1)
            ss += __shfl_xor(ss, off);
        float den = fmaxf(sqrtf(ss), 1e-12f);
        if (lane < 32) out[(size_t)n * KANCH + lane] = q / den;
    }
}

// ---------------------------------------------------------------------------
extern "C" void kernel_launch(void* const* d_in, const int* in_sizes, int n_in,
                              void* d_out, int out_size, void* d_ws, size_t ws_size,
                              hipStream_t stream)
{
    const float* feat  = (const float*)d_in[0];
    const float* dists = (const float*)d_in[1];
    const int*   src   = (const int*)d_in[2];
    const int*   dst   = (const int*)d_in[3];
    const float* w_pre = (const float*)d_in[4];
    const float* b_pre = (const float*)d_in[5];
    const float* Wu1   = (const float*)d_in[6];
    const float* bu1   = (const float*)d_in[7];
    const float* Wv1   = (const float*)d_in[8];
    const float* bv1   = (const float*)d_in[9];
    // d_in[10]=wp1, d_in[11]=bp1: layer-1 position output is discarded
    const float* Wu2   = (const float*)d_in[12];
    const float* bu2   = (const float*)d_in[13];
    const float* Wv2   = (const float*)d_in[14];
    const float* bv2   = (const float*)d_in[15];
    const float* wp2   = (const float*)d_in[16];
    const float* bp2   = (const float*)d_in[17];
    float* out = (float*)d_out;

    // workspace (~19.3 MB)
    unsigned short* wcat1 = (unsigned short*)d_ws;           // 16384 us
    float* bias1 = (float*)(wcat1 + 16384);                  // 128 f
    unsigned short* wcat2 = (unsigned short*)(bias1 + 128);  // 4096 us
    float* bias2 = (float*)(wcat2 + 4096);                   // 64 f
    unsigned short* u1b = (unsigned short*)(bias2 + 64);     // NN*64
    unsigned short* v1b = u1b + (size_t)NN * 64;             // NN*64
    unsigned short* x2b = v1b + (size_t)NN * 64;             // NN*64
    unsigned short* u2b = u1b;   // alias: u1b dead after k_gather1
    unsigned short* v2b = v1b;   // alias: v1b dead after k_gather1

    k_prep<<<81, 256, 0, stream>>>(w_pre, b_pre, Wu1, bu1, Wv1, bv1,
                                   Wu2, bu2, Wv2, bv2,
                                   wcat1, bias1, wcat2, bias2);
    k_gemm1<<<782, 256, 0, stream>>>(feat, wcat1, bias1, u1b, v1b, NN / 16);
    k_gather1<<<2048, 256, 0, stream>>>((const ushort4*)u1b, (const ushort4*)v1b,
                                        src, dst, dists, (ushort4*)x2b);
    k_gemm2<<<782, 256, 0, stream>>>(x2b, wcat2, bias2, u2b, v2b, NN / 16);
    k_out<<<2048, 256, 0, stream>>>((const ushort4*)u2b, (const ushort4*)v2b,
                                    src, dst, dists, wp2, bp2, out);
}